// Round 1
// baseline (439.036 us; speedup 1.0000x reference)
//
#include <hip/hip_runtime.h>

typedef int   int4v   __attribute__((ext_vector_type(4)));
typedef float float4v __attribute__((ext_vector_type(4)));

// 5th-order NF4 polynomial, Horner form, fp32 — same arithmetic as reference.
__device__ __forceinline__ float nf4_poly(float x) {
    return x * (x * (x * (x * (1.82943132356953e-05f * x - 0.00068587779130373f)
                          + 0.0100420261313669f) - 0.0722703570217226f)
                + 0.346075459755188f) - 0.994166218659335f;
}

// Layout: quants [G=256, gs=32, N=8192] int32 (values 0..15), scales [G, 1, N] fp32.
// Output [G*gs, N] fp32, same flat order as quants.
// Flat element i: g = i >> 18 (gs*N = 2^18), n = i & 8191.
__global__ void __launch_bounds__(256)
nf4_dequant_kernel(const int* __restrict__ q,
                   const float* __restrict__ s,
                   float* __restrict__ out,
                   long long nvec)   // number of 4-element vectors
{
    const long long stride = (long long)gridDim.x * blockDim.x;
    for (long long v = (long long)blockIdx.x * blockDim.x + threadIdx.x;
         v < nvec; v += stride) {
        const long long i = v << 2;                 // element index (aligned to 4)
        int4v qa = *(const int4v*)(q + i);
        const long long g = i >> 18;
        const long long n = i & 8191;               // N=8192, 4-aligned
        float4v sc = *(const float4v*)(s + (g << 13) + n);
        float4v r;
#pragma unroll
        for (int j = 0; j < 4; ++j) {
            int u = qa[j];
            u = (u < 0) ? (u + 16) : u;             // i4tou4
            r[j] = nf4_poly((float)u) * sc[j];
        }
        *(float4v*)(out + i) = r;
    }
}

extern "C" void kernel_launch(void* const* d_in, const int* in_sizes, int n_in,
                              void* d_out, int out_size, void* d_ws, size_t ws_size,
                              hipStream_t stream) {
    const int*   q = (const int*)d_in[0];
    const float* s = (const float*)d_in[1];
    float*     out = (float*)d_out;

    const long long total = (long long)in_sizes[0];   // 67,108,864
    const long long nvec  = total >> 2;               // 16,777,216 float4 units

    const int threads = 256;
    const int blocks  = 4096;                         // grid-stride, ~16 iters/thread
    nf4_dequant_kernel<<<blocks, threads, 0, stream>>>(q, s, out, nvec);
}

// Round 2
// 430.703 us; speedup vs baseline: 1.0193x; 1.0193x over previous
//
#include <hip/hip_runtime.h>

typedef int   int4v   __attribute__((ext_vector_type(4)));
typedef float float4v __attribute__((ext_vector_type(4)));

// 5th-order NF4 polynomial, Horner form, fp32 — same arithmetic as reference.
__device__ __forceinline__ float nf4_poly(float x) {
    return x * (x * (x * (x * (1.82943132356953e-05f * x - 0.00068587779130373f)
                          + 0.0100420261313669f) - 0.0722703570217226f)
                + 0.346075459755188f) - 0.994166218659335f;
}

// Layout: quants [G=256, gs=32, N=8192] int32 (values 0..15), scales [G, 1, N] fp32.
// Output [G*gs, N] fp32, same flat order as quants.
// Flat element i: g = i >> 18 (gs*N = 2^18), n = i & 8191.
// All indices fit in 32 bits (total 2^26 elements, byte offsets < 2^28).
__global__ void __launch_bounds__(256)
nf4_dequant_kernel(const int* __restrict__ q,
                   const float* __restrict__ s,
                   float* __restrict__ out,
                   unsigned nvec)   // number of 4-element vectors
{
    const unsigned stride = gridDim.x * blockDim.x;
    unsigned v = blockIdx.x * blockDim.x + threadIdx.x;
#pragma unroll 4
    for (; v < nvec; v += stride) {
        const unsigned i = v << 2;                  // element index (4-aligned)
        // quants: streamed once — nontemporal to avoid L2/L3 pollution
        int4v qa = __builtin_nontemporal_load((const int4v*)(q + i));
        const unsigned g = i >> 18;                 // group (gs*N = 2^18)
        const unsigned n = i & 8191u;               // column within row, 4-aligned
        // scales: 8 MB total, heavily reused -> normal cached load
        float4v sc = *(const float4v*)(s + (g << 13) + n);
        float4v r;
#pragma unroll
        for (int j = 0; j < 4; ++j) {
            int u = qa[j];
            u = (u < 0) ? (u + 16) : u;             // i4tou4
            r[j] = nf4_poly((float)u) * sc[j];
        }
        // output: streamed once — nontemporal store
        __builtin_nontemporal_store(r, (float4v*)(out + i));
    }
}

extern "C" void kernel_launch(void* const* d_in, const int* in_sizes, int n_in,
                              void* d_out, int out_size, void* d_ws, size_t ws_size,
                              hipStream_t stream) {
    const int*   q = (const int*)d_in[0];
    const float* s = (const float*)d_in[1];
    float*     out = (float*)d_out;

    const unsigned total = (unsigned)in_sizes[0];   // 67,108,864
    const unsigned nvec  = total >> 2;              // 16,777,216 float4 units

    const int threads = 256;
    const int blocks  = 4096;                       // 1M threads, 16 vec/thread
    nf4_dequant_kernel<<<blocks, threads, 0, stream>>>(q, s, out, nvec);
}